// Round 8
// baseline (748.063 us; speedup 1.0000x reference)
//
#include <hip/hip_runtime.h>

static constexpr int FIN = 128;
static constexpr int HD  = 64;
static constexpr int CD  = 40;

// ---------------------------------------------------------------------------
// Dense matvec, LDS-staged: block = 256 threads = 256 nodes.
//  - input tile staged global->LDS in K-chunks of CH, fully coalesced float4
//  - compute: thread = node, acc[O] statically indexed (registers, spill-free
//    per R5), input from LDS (padded stride -> cheap), weights via wave-
//    uniform s_load on the scalar pipe (parallel to VALU)
//  - per k4 group: 1 ds_read_b128 + O FMA-instrs -> FMA-issue-bound
// R5 lesson: per-lane scattered global input loads stall at low occupancy.
// R6 lesson: never o-split across blocks (FETCH x15).
// R7 lesson: lane=output transposed layout has 1 acc chain -> latency-bound.
// ---------------------------------------------------------------------------
template<int K, int CH, int LSTRIDE, int O, bool IN_RELU, bool OUT_RELU>
__global__ __launch_bounds__(256, 2)
void mv_lds_kernel(const float* __restrict__ in, const float* __restrict__ W,
                   const float* __restrict__ bias, float* __restrict__ out, int n)
{
    __shared__ float lds[256 * LSTRIDE];
    const int t = threadIdx.x;
    const int n0 = blockIdx.x * 256;
    const int node = n0 + t;

    float acc[O];
#pragma unroll
    for (int o = 0; o < O; ++o) acc[o] = bias[o];

    constexpr int VPN = CH / 4;                 // float4 loads per node-chunk
    constexpr int NCH = (K + CH - 1) / CH;      // k-chunks

#pragma unroll 1
    for (int c = 0; c < NCH; ++c) {
        const int kbase = c * CH;
        // ---- stage chunk: 256 nodes x CH floats, coalesced ----
#pragma unroll 1
        for (int f = t; f < 256 * VPN; f += 256) {
            int nl = f / VPN;
            int k4 = (f - nl * VPN) * 4;
            int gn = n0 + nl;
            float4 v;
            if (gn < n)
                v = *reinterpret_cast<const float4*>(in + (size_t)gn * K + kbase + k4);
            else
                v = make_float4(0.f, 0.f, 0.f, 0.f);
            if (IN_RELU) {
                v.x = fmaxf(v.x, 0.f); v.y = fmaxf(v.y, 0.f);
                v.z = fmaxf(v.z, 0.f); v.w = fmaxf(v.w, 0.f);
            }
            *reinterpret_cast<float4*>(&lds[nl * LSTRIDE + k4]) = v;
        }
        __syncthreads();
        // ---- compute: FMA burst from LDS + scalar-pipe weights ----
        if (node < n) {
#pragma unroll
            for (int k4 = 0; k4 < CH; k4 += 4) {
                float4 v = *reinterpret_cast<const float4*>(&lds[t * LSTRIDE + k4]);
#pragma unroll
                for (int o = 0; o < O; ++o) {
                    const float* wr = W + (size_t)o * K + kbase + k4;  // uniform -> s_load
                    acc[o] = fmaf(v.x, wr[0], acc[o]);
                    acc[o] = fmaf(v.y, wr[1], acc[o]);
                    acc[o] = fmaf(v.z, wr[2], acc[o]);
                    acc[o] = fmaf(v.w, wr[3], acc[o]);
                }
            }
        }
        __syncthreads();
    }

    if (node < n) {
        float* orow = out + (size_t)node * O;
#pragma unroll
        for (int o = 0; o < O; o += 4) {
            float4 r;
            r.x = OUT_RELU ? fmaxf(acc[o],     0.f) : acc[o];
            r.y = OUT_RELU ? fmaxf(acc[o + 1], 0.f) : acc[o + 1];
            r.z = OUT_RELU ? fmaxf(acc[o + 2], 0.f) : acc[o + 2];
            r.w = OUT_RELU ? fmaxf(acc[o + 3], 0.f) : acc[o + 3];
            *reinterpret_cast<float4*>(orow + o) = r;
        }
    }
}

// ---------------------------------------------------------------------------
// CSR build.
// ---------------------------------------------------------------------------
__global__ __launch_bounds__(256)
void hist_kernel(const int* __restrict__ dst, int* __restrict__ deg, int e)
{
    int i = blockIdx.x * 256 + threadIdx.x;
    if (i < e) atomicAdd(&deg[dst[i]], 1);
}

__global__ __launch_bounds__(256)
void chunksum_kernel(const int* __restrict__ deg, int* __restrict__ chunkSum, int n)
{
    __shared__ int s[256];
    int t = threadIdx.x;
    int base = blockIdx.x * 1024 + t * 4;
    int v = 0;
#pragma unroll
    for (int i = 0; i < 4; ++i) if (base + i < n) v += deg[base + i];
    s[t] = v; __syncthreads();
    for (int off = 128; off > 0; off >>= 1) {
        if (t < off) s[t] += s[t + off];
        __syncthreads();
    }
    if (t == 0) chunkSum[blockIdx.x] = s[0];
}

__global__ __launch_bounds__(128)
void scanchunks_kernel(int* __restrict__ chunkSum, int nchunks)
{
    __shared__ int s[128];
    int t = threadIdx.x;
    int v = (t < nchunks) ? chunkSum[t] : 0;
    s[t] = v; __syncthreads();
    for (int off = 1; off < 128; off <<= 1) {
        int a = (t >= off) ? s[t - off] : 0;
        __syncthreads();
        s[t] += a;
        __syncthreads();
    }
    if (t < nchunks) chunkSum[t] = s[t] - v;   // exclusive
}

__global__ __launch_bounds__(256)
void scanwithin_kernel(const int* __restrict__ deg, const int* __restrict__ chunkOff,
                       int* __restrict__ rowptr, int n)
{
    __shared__ int s[256];
    int t = threadIdx.x;
    int base = blockIdx.x * 1024 + t * 4;
    int v[4]; int sum = 0;
#pragma unroll
    for (int i = 0; i < 4; ++i) { v[i] = (base + i < n) ? deg[base + i] : 0; sum += v[i]; }
    s[t] = sum; __syncthreads();
    for (int off = 1; off < 256; off <<= 1) {
        int a = (t >= off) ? s[t - off] : 0;
        __syncthreads();
        s[t] += a;
        __syncthreads();
    }
    int p = s[t] - sum + chunkOff[blockIdx.x];
#pragma unroll
    for (int i = 0; i < 4; ++i) {
        if (base + i < n) rowptr[base + i] = p;
        p += v[i];
    }
}

__global__ __launch_bounds__(256)
void fill_kernel(const int* __restrict__ src, const int* __restrict__ dst,
                 int* __restrict__ rowptr, int* __restrict__ eidx, int e)
{
    int i = blockIdx.x * 256 + threadIdx.x;
    if (i >= e) return;
    int pos = atomicAdd(&rowptr[dst[i]], 1);
    eidx[pos] = src[i];
}

// ---------------------------------------------------------------------------
// Gather: agg[d][c] = h[d][c] + sum_{e: dst=d} h[src_e][c].
// One wave per node, lane = channel.
// ---------------------------------------------------------------------------
template<int D>
__global__ __launch_bounds__(256)
void gather_kernel(const int* __restrict__ rowptr_end, const int* __restrict__ deg,
                   const int* __restrict__ eidx, const float* __restrict__ h,
                   float* __restrict__ agg, int n)
{
    int wave = threadIdx.x >> 6;
    int lane = threadIdx.x & 63;
    int node = blockIdx.x * 4 + wave;
    if (node >= n) return;
    bool act = (lane < D);
    float acc = act ? h[(size_t)node * D + lane] : 0.f;
    int end = rowptr_end[node];
    int start = end - deg[node];
    for (int base = start; base < end; base += 64) {
        int m = min(64, end - base);
        int sv = (lane < m) ? eidx[base + lane] : 0;
        for (int j = 0; j < m; ++j) {
            int s = __shfl(sv, j, 64);
            if (act) acc += h[(size_t)s * D + lane];
        }
    }
    if (act) agg[(size_t)node * D + lane] = acc;
}

extern "C" void kernel_launch(void* const* d_in, const int* in_sizes, int n_in,
                              void* d_out, int out_size, void* d_ws, size_t ws_size,
                              hipStream_t stream)
{
    const float* x      = (const float*)d_in[0];
    const int*   ei     = (const int*)d_in[1];
    const float* w1_lin = (const float*)d_in[2];
    const float* b1_lin = (const float*)d_in[3];
    const float* w1_o1  = (const float*)d_in[4];
    const float* b1_o1  = (const float*)d_in[5];
    const float* w1_o2  = (const float*)d_in[6];
    const float* b1_o2  = (const float*)d_in[7];
    const float* w2_lin = (const float*)d_in[8];
    const float* b2_lin = (const float*)d_in[9];
    const float* w2_o1  = (const float*)d_in[10];
    const float* b2_o1  = (const float*)d_in[11];
    const float* w2_o2  = (const float*)d_in[12];
    const float* b2_o2  = (const float*)d_in[13];

    const int n = in_sizes[0] / FIN;   // 100000
    const int e = in_sizes[1] / 2;     // 1000000
    const int* src = ei;
    const int* dst = ei + e;

    // Two float buffers in d_ws, strict ping-pong:
    float* ws0 = (float*)d_ws;
    float* ws1 = ws0 + (size_t)n * HD;
    float* outp = (float*)d_out;

    // CSR arrays live in d_out (16 MB; last consumer is gather40, before the
    // final mv writes d_out).
    int* eidx     = (int*)d_out;
    int* deg      = eidx + e;
    int* rowptr   = deg + n;
    int* chunkSum = rowptr + n;

    const int nchunks = (n + 1023) / 1024;        // 98 (<=128)
    const int egrid   = (e + 255) / 256;
    const int ngrid   = (n + 255) / 256;
    const int ggrid   = (n + 3) / 4;

    // ---- CSR build (reused by both layers) ----
    hipMemsetAsync(deg, 0, (size_t)n * sizeof(int), stream);
    hist_kernel<<<egrid, 256, 0, stream>>>(dst, deg, e);
    chunksum_kernel<<<nchunks, 256, 0, stream>>>(deg, chunkSum, n);
    scanchunks_kernel<<<1, 128, 0, stream>>>(chunkSum, nchunks);
    scanwithin_kernel<<<nchunks, 256, 0, stream>>>(deg, chunkSum, rowptr, n);
    fill_kernel<<<egrid, 256, 0, stream>>>(src, dst, rowptr, eidx, e);

    // ---- conv1 ----
    // h1 = x @ w1_lin.T + b            : ws0
    mv_lds_kernel<FIN, 32, 36, HD, false, false><<<ngrid, 256, 0, stream>>>(
        x, w1_lin, b1_lin, ws0, n);
    // agg1 = h1 + scatter              : ws1
    gather_kernel<HD><<<ggrid, 256, 0, stream>>>(rowptr, deg, eidx, ws0, ws1, n);
    // u1 = relu(o1 @ relu(agg1) + b)   : ws0
    mv_lds_kernel<HD, 32, 36, HD, true, true><<<ngrid, 256, 0, stream>>>(
        ws1, w1_o1, b1_o1, ws0, n);
    // hmid = relu(o2 @ u1 + b)         : ws1
    mv_lds_kernel<HD, 32, 36, HD, false, true><<<ngrid, 256, 0, stream>>>(
        ws0, w1_o2, b1_o2, ws1, n);

    // ---- conv2 ----
    // h2 = hmid @ w2_lin.T + b         : ws0
    mv_lds_kernel<HD, 32, 36, CD, false, false><<<ngrid, 256, 0, stream>>>(
        ws1, w2_lin, b2_lin, ws0, n);
    // agg2 = h2 + scatter              : ws1
    gather_kernel<CD><<<ggrid, 256, 0, stream>>>(rowptr, deg, eidx, ws0, ws1, n);
    // u2 = relu(o1 @ relu(agg2) + b)   : ws0
    mv_lds_kernel<CD, 40, 44, CD, true, true><<<ngrid, 256, 0, stream>>>(
        ws1, w2_o1, b2_o1, ws0, n);
    // out = o2 @ u2 + b                : d_out
    mv_lds_kernel<CD, 40, 44, CD, false, false><<<ngrid, 256, 0, stream>>>(
        ws0, w2_o2, b2_o2, outp, n);
}

// Round 9
// 706.594 us; speedup vs baseline: 1.0587x; 1.0587x over previous
//
#include <hip/hip_runtime.h>

static constexpr int FIN = 128;
static constexpr int HD  = 64;
static constexpr int CD  = 40;

// ---------------------------------------------------------------------------
// Dense matvec, wave-split outputs: block = 256 thr = 4 waves; 64 nodes/block.
//  - input tile (64 x K) staged once into LDS, shared by all 4 waves
//    (o-split WITHIN block -> no FETCH multiplication, unlike R6's y-split)
//  - wave w computes output rows [w*OG,(w+1)*OG): weight addr wave-uniform
//    -> s_load; acc[OG] statically indexed -> registers
//  - grid = n/64 = 1563 blocks (4x R8) -> fixes the 1.5-blocks/CU occupancy
//    cap that left s_load latency unhidden (R8: VALUBusy 12%, occ 16%)
//  - LDS row stride K+4: odd dword count, gcd(.,32)=1 -> conflict-free
// ---------------------------------------------------------------------------
template<int K, int O, int OG, bool IN_RELU, bool OUT_RELU>
__global__ __launch_bounds__(256, 4)
void mv_tile_kernel(const float* __restrict__ in, const float* __restrict__ W,
                    const float* __restrict__ bias, float* __restrict__ out, int n)
{
    constexpr int LSTRIDE = K + 4;
    __shared__ float lds[64 * LSTRIDE];
    const int t    = threadIdx.x;
    const int wave = t >> 6;
    const int lane = t & 63;
    const int n0   = blockIdx.x * 64;

    // ---- stage 64 node-rows x K floats, coalesced float4 ----
    constexpr int VPN  = K / 4;          // float4s per row
    constexpr int TOT4 = 64 * VPN;
#pragma unroll
    for (int f = t; f < TOT4; f += 256) {
        int nl = f / VPN;
        int k4 = (f - nl * VPN) * 4;
        int gn = n0 + nl;
        float4 v;
        if (gn < n)
            v = *reinterpret_cast<const float4*>(in + (size_t)gn * K + k4);
        else
            v = make_float4(0.f, 0.f, 0.f, 0.f);
        if (IN_RELU) {
            v.x = fmaxf(v.x, 0.f); v.y = fmaxf(v.y, 0.f);
            v.z = fmaxf(v.z, 0.f); v.w = fmaxf(v.w, 0.f);
        }
        *reinterpret_cast<float4*>(&lds[nl * LSTRIDE + k4]) = v;
    }
    __syncthreads();

    // ---- compute: this wave's OG output rows for node = n0 + lane ----
    const int og0 = wave * OG;
    float acc[OG];
#pragma unroll
    for (int oo = 0; oo < OG; ++oo) acc[oo] = bias[og0 + oo];

    const float* Wb = W + (size_t)og0 * K;
#pragma unroll 2
    for (int k4 = 0; k4 < K; k4 += 4) {
        float4 v = *reinterpret_cast<const float4*>(&lds[lane * LSTRIDE + k4]);
#pragma unroll
        for (int oo = 0; oo < OG; ++oo) {
            const float* wr = Wb + (size_t)oo * K + k4;   // wave-uniform -> s_load
            acc[oo] = fmaf(v.x, wr[0], acc[oo]);
            acc[oo] = fmaf(v.y, wr[1], acc[oo]);
            acc[oo] = fmaf(v.z, wr[2], acc[oo]);
            acc[oo] = fmaf(v.w, wr[3], acc[oo]);
        }
    }

    const int node = n0 + lane;
    if (node < n) {
        float* orow = out + (size_t)node * O + og0;
#pragma unroll
        for (int oo = 0; oo < OG; oo += 2) {   // float2: og0 may be odd-x4 (OG=10)
            float2 r;
            r.x = OUT_RELU ? fmaxf(acc[oo],     0.f) : acc[oo];
            r.y = OUT_RELU ? fmaxf(acc[oo + 1], 0.f) : acc[oo + 1];
            *reinterpret_cast<float2*>(orow + oo) = r;
        }
    }
}

// ---------------------------------------------------------------------------
// CSR build.
// ---------------------------------------------------------------------------
__global__ __launch_bounds__(256)
void hist_kernel(const int* __restrict__ dst, int* __restrict__ deg, int e)
{
    int i = blockIdx.x * 256 + threadIdx.x;
    if (i < e) atomicAdd(&deg[dst[i]], 1);
}

__global__ __launch_bounds__(256)
void chunksum_kernel(const int* __restrict__ deg, int* __restrict__ chunkSum, int n)
{
    __shared__ int s[256];
    int t = threadIdx.x;
    int base = blockIdx.x * 1024 + t * 4;
    int v = 0;
#pragma unroll
    for (int i = 0; i < 4; ++i) if (base + i < n) v += deg[base + i];
    s[t] = v; __syncthreads();
    for (int off = 128; off > 0; off >>= 1) {
        if (t < off) s[t] += s[t + off];
        __syncthreads();
    }
    if (t == 0) chunkSum[blockIdx.x] = s[0];
}

__global__ __launch_bounds__(128)
void scanchunks_kernel(int* __restrict__ chunkSum, int nchunks)
{
    __shared__ int s[128];
    int t = threadIdx.x;
    int v = (t < nchunks) ? chunkSum[t] : 0;
    s[t] = v; __syncthreads();
    for (int off = 1; off < 128; off <<= 1) {
        int a = (t >= off) ? s[t - off] : 0;
        __syncthreads();
        s[t] += a;
        __syncthreads();
    }
    if (t < nchunks) chunkSum[t] = s[t] - v;   // exclusive
}

__global__ __launch_bounds__(256)
void scanwithin_kernel(const int* __restrict__ deg, const int* __restrict__ chunkOff,
                       int* __restrict__ rowptr, int n)
{
    __shared__ int s[256];
    int t = threadIdx.x;
    int base = blockIdx.x * 1024 + t * 4;
    int v[4]; int sum = 0;
#pragma unroll
    for (int i = 0; i < 4; ++i) { v[i] = (base + i < n) ? deg[base + i] : 0; sum += v[i]; }
    s[t] = sum; __syncthreads();
    for (int off = 1; off < 256; off <<= 1) {
        int a = (t >= off) ? s[t - off] : 0;
        __syncthreads();
        s[t] += a;
        __syncthreads();
    }
    int p = s[t] - sum + chunkOff[blockIdx.x];
#pragma unroll
    for (int i = 0; i < 4; ++i) {
        if (base + i < n) rowptr[base + i] = p;
        p += v[i];
    }
}

__global__ __launch_bounds__(256)
void fill_kernel(const int* __restrict__ src, const int* __restrict__ dst,
                 int* __restrict__ rowptr, int* __restrict__ eidx, int e)
{
    int i = blockIdx.x * 256 + threadIdx.x;
    if (i >= e) return;
    int pos = atomicAdd(&rowptr[dst[i]], 1);
    eidx[pos] = src[i];
}

// ---------------------------------------------------------------------------
// Gather: agg[d][c] = h[d][c] + sum_{e: dst=d} h[src_e][c].
// One wave per node, lane = channel.
// ---------------------------------------------------------------------------
template<int D>
__global__ __launch_bounds__(256)
void gather_kernel(const int* __restrict__ rowptr_end, const int* __restrict__ deg,
                   const int* __restrict__ eidx, const float* __restrict__ h,
                   float* __restrict__ agg, int n)
{
    int wave = threadIdx.x >> 6;
    int lane = threadIdx.x & 63;
    int node = blockIdx.x * 4 + wave;
    if (node >= n) return;
    bool act = (lane < D);
    float acc = act ? h[(size_t)node * D + lane] : 0.f;
    int end = rowptr_end[node];
    int start = end - deg[node];
    for (int base = start; base < end; base += 64) {
        int m = min(64, end - base);
        int sv = (lane < m) ? eidx[base + lane] : 0;
        for (int j = 0; j < m; ++j) {
            int s = __shfl(sv, j, 64);
            if (act) acc += h[(size_t)s * D + lane];
        }
    }
    if (act) agg[(size_t)node * D + lane] = acc;
}

extern "C" void kernel_launch(void* const* d_in, const int* in_sizes, int n_in,
                              void* d_out, int out_size, void* d_ws, size_t ws_size,
                              hipStream_t stream)
{
    const float* x      = (const float*)d_in[0];
    const int*   ei     = (const int*)d_in[1];
    const float* w1_lin = (const float*)d_in[2];
    const float* b1_lin = (const float*)d_in[3];
    const float* w1_o1  = (const float*)d_in[4];
    const float* b1_o1  = (const float*)d_in[5];
    const float* w1_o2  = (const float*)d_in[6];
    const float* b1_o2  = (const float*)d_in[7];
    const float* w2_lin = (const float*)d_in[8];
    const float* b2_lin = (const float*)d_in[9];
    const float* w2_o1  = (const float*)d_in[10];
    const float* b2_o1  = (const float*)d_in[11];
    const float* w2_o2  = (const float*)d_in[12];
    const float* b2_o2  = (const float*)d_in[13];

    const int n = in_sizes[0] / FIN;   // 100000
    const int e = in_sizes[1] / 2;     // 1000000
    const int* src = ei;
    const int* dst = ei + e;

    // Two float buffers in d_ws, strict ping-pong:
    float* ws0 = (float*)d_ws;
    float* ws1 = ws0 + (size_t)n * HD;
    float* outp = (float*)d_out;

    // CSR arrays live in d_out (16 MB; last consumer is gather40, before the
    // final mv writes d_out).
    int* eidx     = (int*)d_out;
    int* deg      = eidx + e;
    int* rowptr   = deg + n;
    int* chunkSum = rowptr + n;

    const int nchunks = (n + 1023) / 1024;        // 98 (<=128)
    const int egrid   = (e + 255) / 256;
    const int tgrid   = (n + 63) / 64;            // mv_tile grid: 1563 blocks
    const int ggrid   = (n + 3) / 4;

    // ---- CSR build (reused by both layers) ----
    hipMemsetAsync(deg, 0, (size_t)n * sizeof(int), stream);
    hist_kernel<<<egrid, 256, 0, stream>>>(dst, deg, e);
    chunksum_kernel<<<nchunks, 256, 0, stream>>>(deg, chunkSum, n);
    scanchunks_kernel<<<1, 128, 0, stream>>>(chunkSum, nchunks);
    scanwithin_kernel<<<nchunks, 256, 0, stream>>>(deg, chunkSum, rowptr, n);
    fill_kernel<<<egrid, 256, 0, stream>>>(src, dst, rowptr, eidx, e);

    // ---- conv1 ----
    // h1 = x @ w1_lin.T + b            : ws0
    mv_tile_kernel<FIN, HD, 16, false, false><<<tgrid, 256, 0, stream>>>(
        x, w1_lin, b1_lin, ws0, n);
    // agg1 = h1 + scatter              : ws1
    gather_kernel<HD><<<ggrid, 256, 0, stream>>>(rowptr, deg, eidx, ws0, ws1, n);
    // u1 = relu(o1 @ relu(agg1) + b)   : ws0
    mv_tile_kernel<HD, HD, 16, true, true><<<tgrid, 256, 0, stream>>>(
        ws1, w1_o1, b1_o1, ws0, n);
    // hmid = relu(o2 @ u1 + b)         : ws1
    mv_tile_kernel<HD, HD, 16, false, true><<<tgrid, 256, 0, stream>>>(
        ws0, w1_o2, b1_o2, ws1, n);

    // ---- conv2 ----
    // h2 = hmid @ w2_lin.T + b         : ws0
    mv_tile_kernel<HD, CD, 10, false, false><<<tgrid, 256, 0, stream>>>(
        ws1, w2_lin, b2_lin, ws0, n);
    // agg2 = h2 + scatter              : ws1
    gather_kernel<CD><<<ggrid, 256, 0, stream>>>(rowptr, deg, eidx, ws0, ws1, n);
    // u2 = relu(o1 @ relu(agg2) + b)   : ws0
    mv_tile_kernel<CD, CD, 10, true, true><<<tgrid, 256, 0, stream>>>(
        ws1, w2_o1, b2_o1, ws0, n);
    // out = o2 @ u2 + b                : d_out
    mv_tile_kernel<CD, CD, 10, false, false><<<tgrid, 256, 0, stream>>>(
        ws0, w2_o2, b2_o2, outp, n);
}

// Round 10
// 473.082 us; speedup vs baseline: 1.5813x; 1.4936x over previous
//
#include <hip/hip_runtime.h>

static constexpr int FIN = 128;
static constexpr int HD  = 64;
static constexpr int CD  = 40;

typedef __attribute__((ext_vector_type(8))) short short8;   // 8 bf16 = 4 VGPR
typedef __attribute__((ext_vector_type(4))) float f32x4;    // MFMA acc

__device__ __forceinline__ unsigned short f2b(float f)      // fp32->bf16 RNE
{
    union { float f; unsigned u; } x; x.f = f;
    unsigned u = x.u;
    return (unsigned short)((u + 0x7FFF + ((u >> 16) & 1)) >> 16);
}

// ---------------------------------------------------------------------------
// Weight convert: fp32 W[Oin][Kin] -> bf16 Wbf[Op][Kp], zero-padded.
// ---------------------------------------------------------------------------
template<int Kin, int Kp, int Oin, int Op>
__global__ __launch_bounds__(256)
void wconv_kernel(const float* __restrict__ W, unsigned short* __restrict__ Wbf)
{
    int i = blockIdx.x * 256 + threadIdx.x;
    if (i >= Op * Kp) return;
    int o = i / Kp, k = i - o * Kp;
    float v = (o < Oin && k < Kin) ? W[o * Kin + k] : 0.f;
    Wbf[i] = f2b(v);
}

// ---------------------------------------------------------------------------
// Dense matvec on MFMA (bf16 in, fp32 acc).  Block = 256 thr = 4 waves =
// 64 nodes.  Input tile staged fp32->bf16 into LDS (stride KP+8 -> 2-way
// bank conflicts only = free).  Wave w computes nodes [w*16,(w+1)*16) x all
// OP outputs as OP/16 C-tiles, K-loop = KP/32 MFMAs each.
// Fragment layouts (m89/m91/m120-verified):
//   A: lane holds A[m=lane&15][k=quad*8+j]            (ds_read_b128)
//   B: lane holds B[k=quad*8+j][o=lane&15] = Wbf[o][k] (16B global, L1-hot)
//   D: lane&15 = col(o), quad*4+reg = row(node)
// R5-R9 lesson: fp32 VALU matvec plateaus ~126us on operand delivery;
// MFMA makes these kernels staging/HBM-bound instead.
// ---------------------------------------------------------------------------
template<int KP, int OP, int K, int O, bool IN_RELU, bool OUT_RELU>
__global__ __launch_bounds__(256)
void mv_mfma_kernel(const float* __restrict__ in, const unsigned short* __restrict__ Wbf,
                    const float* __restrict__ bias, float* __restrict__ out, int n)
{
    constexpr int KS = KP + 8;                 // bf16 elems per LDS row
    __shared__ unsigned short lds[64 * KS];
    const int t  = threadIdx.x;
    const int n0 = blockIdx.x * 64;

    // ---- stage 64 rows x KP bf16 (coalesced fp32 float4 reads) ----
    constexpr int V4 = KP / 4;
#pragma unroll
    for (int f = t; f < 64 * V4; f += 256) {
        int row = f / V4;
        int k4  = (f - row * V4) * 4;
        int gn  = n0 + row;
        float4 v = make_float4(0.f, 0.f, 0.f, 0.f);
        if (gn < n && k4 < K)
            v = *reinterpret_cast<const float4*>(in + (size_t)gn * K + k4);
        if (IN_RELU) {
            v.x = fmaxf(v.x, 0.f); v.y = fmaxf(v.y, 0.f);
            v.z = fmaxf(v.z, 0.f); v.w = fmaxf(v.w, 0.f);
        }
        ushort4 b;
        b.x = f2b(v.x); b.y = f2b(v.y); b.z = f2b(v.z); b.w = f2b(v.w);
        *reinterpret_cast<ushort4*>(&lds[row * KS + k4]) = b;
    }
    __syncthreads();

    const int wave = t >> 6, lane = t & 63;
    const int quad = lane >> 4, l16 = lane & 15;
    const int m0   = wave * 16;

    // ---- A fragments from LDS ----
    constexpr int NKT = KP / 32;
    short8 a[NKT];
#pragma unroll
    for (int kt = 0; kt < NKT; ++kt)
        a[kt] = *reinterpret_cast<const short8*>(
            &lds[(m0 + l16) * KS + kt * 32 + quad * 8]);

    // ---- MFMA: OP/16 C-tiles ----
    constexpr int NOT = OP / 16;
    f32x4 acc[NOT];
#pragma unroll
    for (int ot = 0; ot < NOT; ++ot) acc[ot] = (f32x4){0.f, 0.f, 0.f, 0.f};
#pragma unroll
    for (int ot = 0; ot < NOT; ++ot) {
        const unsigned short* Wrow = Wbf + (size_t)(ot * 16 + l16) * KP + quad * 8;
#pragma unroll
        for (int kt = 0; kt < NKT; ++kt) {
            short8 b = *reinterpret_cast<const short8*>(Wrow + kt * 32);
            acc[ot] = __builtin_amdgcn_mfma_f32_16x16x32_bf16(a[kt], b, acc[ot], 0, 0, 0);
        }
    }

    // ---- epilogue: D[row=quad*4+r][col=l16] ----
#pragma unroll
    for (int ot = 0; ot < NOT; ++ot) {
        int o = ot * 16 + l16;
        if (o < O) {
            float bv = bias[o];
#pragma unroll
            for (int r = 0; r < 4; ++r) {
                int node = n0 + m0 + quad * 4 + r;
                if (node < n) {
                    float v = acc[ot][r] + bv;
                    if (OUT_RELU) v = fmaxf(v, 0.f);
                    out[(size_t)node * O + o] = v;
                }
            }
        }
    }
}

// ---------------------------------------------------------------------------
// CSR build.
// ---------------------------------------------------------------------------
__global__ __launch_bounds__(256)
void hist_kernel(const int* __restrict__ dst, int* __restrict__ deg, int e)
{
    int i = blockIdx.x * 256 + threadIdx.x;
    if (i < e) atomicAdd(&deg[dst[i]], 1);
}

__global__ __launch_bounds__(256)
void chunksum_kernel(const int* __restrict__ deg, int* __restrict__ chunkSum, int n)
{
    __shared__ int s[256];
    int t = threadIdx.x;
    int base = blockIdx.x * 1024 + t * 4;
    int v = 0;
#pragma unroll
    for (int i = 0; i < 4; ++i) if (base + i < n) v += deg[base + i];
    s[t] = v; __syncthreads();
    for (int off = 128; off > 0; off >>= 1) {
        if (t < off) s[t] += s[t + off];
        __syncthreads();
    }
    if (t == 0) chunkSum[blockIdx.x] = s[0];
}

__global__ __launch_bounds__(128)
void scanchunks_kernel(int* __restrict__ chunkSum, int nchunks)
{
    __shared__ int s[128];
    int t = threadIdx.x;
    int v = (t < nchunks) ? chunkSum[t] : 0;
    s[t] = v; __syncthreads();
    for (int off = 1; off < 128; off <<= 1) {
        int a = (t >= off) ? s[t - off] : 0;
        __syncthreads();
        s[t] += a;
        __syncthreads();
    }
    if (t < nchunks) chunkSum[t] = s[t] - v;   // exclusive
}

__global__ __launch_bounds__(256)
void scanwithin_kernel(const int* __restrict__ deg, const int* __restrict__ chunkOff,
                       int* __restrict__ rowptr, int n)
{
    __shared__ int s[256];
    int t = threadIdx.x;
    int base = blockIdx.x * 1024 + t * 4;
    int v[4]; int sum = 0;
#pragma unroll
    for (int i = 0; i < 4; ++i) { v[i] = (base + i < n) ? deg[base + i] : 0; sum += v[i]; }
    s[t] = sum; __syncthreads();
    for (int off = 1; off < 256; off <<= 1) {
        int a = (t >= off) ? s[t - off] : 0;
        __syncthreads();
        s[t] += a;
        __syncthreads();
    }
    int p = s[t] - sum + chunkOff[blockIdx.x];
#pragma unroll
    for (int i = 0; i < 4; ++i) {
        if (base + i < n) rowptr[base + i] = p;
        p += v[i];
    }
}

__global__ __launch_bounds__(256)
void fill_kernel(const int* __restrict__ src, const int* __restrict__ dst,
                 int* __restrict__ rowptr, int* __restrict__ eidx, int e)
{
    int i = blockIdx.x * 256 + threadIdx.x;
    if (i >= e) return;
    int pos = atomicAdd(&rowptr[dst[i]], 1);
    eidx[pos] = src[i];
}

// ---------------------------------------------------------------------------
// Gather: agg[d][c] = h[d][c] + sum_{e: dst=d} h[src_e][c].
// One wave per node, lane = channel.
// ---------------------------------------------------------------------------
template<int D>
__global__ __launch_bounds__(256)
void gather_kernel(const int* __restrict__ rowptr_end, const int* __restrict__ deg,
                   const int* __restrict__ eidx, const float* __restrict__ h,
                   float* __restrict__ agg, int n)
{
    int wave = threadIdx.x >> 6;
    int lane = threadIdx.x & 63;
    int node = blockIdx.x * 4 + wave;
    if (node >= n) return;
    bool act = (lane < D);
    float acc = act ? h[(size_t)node * D + lane] : 0.f;
    int end = rowptr_end[node];
    int start = end - deg[node];
    for (int base = start; base < end; base += 64) {
        int m = min(64, end - base);
        int sv = (lane < m) ? eidx[base + lane] : 0;
        for (int j = 0; j < m; ++j) {
            int s = __shfl(sv, j, 64);
            if (act) acc += h[(size_t)s * D + lane];
        }
    }
    if (act) agg[(size_t)node * D + lane] = acc;
}

extern "C" void kernel_launch(void* const* d_in, const int* in_sizes, int n_in,
                              void* d_out, int out_size, void* d_ws, size_t ws_size,
                              hipStream_t stream)
{
    const float* x      = (const float*)d_in[0];
    const int*   ei     = (const int*)d_in[1];
    const float* w1_lin = (const float*)d_in[2];
    const float* b1_lin = (const float*)d_in[3];
    const float* w1_o1  = (const float*)d_in[4];
    const float* b1_o1  = (const float*)d_in[5];
    const float* w1_o2  = (const float*)d_in[6];
    const float* b1_o2  = (const float*)d_in[7];
    const float* w2_lin = (const float*)d_in[8];
    const float* b2_lin = (const float*)d_in[9];
    const float* w2_o1  = (const float*)d_in[10];
    const float* b2_o1  = (const float*)d_in[11];
    const float* w2_o2  = (const float*)d_in[12];
    const float* b2_o2  = (const float*)d_in[13];

    const int n = in_sizes[0] / FIN;   // 100000
    const int e = in_sizes[1] / 2;     // 1000000
    const int* src = ei;
    const int* dst = ei + e;

    // d_ws: two fp32 ping-pong buffers + bf16 weight copies (51.2 KB extra).
    float* ws0 = (float*)d_ws;
    float* ws1 = ws0 + (size_t)n * HD;
    unsigned short* wb = (unsigned short*)(ws1 + (size_t)n * HD);
    unsigned short* wb1_lin = wb;                 // [64][128]
    unsigned short* wb1_o1  = wb1_lin + 64 * 128; // [64][64]
    unsigned short* wb1_o2  = wb1_o1  + 64 * 64;  // [64][64]
    unsigned short* wb2_lin = wb1_o2  + 64 * 64;  // [48][64]
    unsigned short* wb2_o1  = wb2_lin + 48 * 64;  // [48][64]
    unsigned short* wb2_o2  = wb2_o1  + 48 * 64;  // [48][64]
    float* outp = (float*)d_out;

    // CSR arrays live in d_out (consumed before the final mv writes d_out).
    int* eidx     = (int*)d_out;
    int* deg      = eidx + e;
    int* rowptr   = deg + n;
    int* chunkSum = rowptr + n;

    const int nchunks = (n + 1023) / 1024;        // 98 (<=128)
    const int egrid   = (e + 255) / 256;
    const int tgrid   = (n + 63) / 64;            // 1563 blocks
    const int ggrid   = (n + 3) / 4;

    // ---- bf16 weight conversion (tiny) ----
    wconv_kernel<128, 128, 64, 64><<<(64 * 128 + 255) / 256, 256, 0, stream>>>(w1_lin, wb1_lin);
    wconv_kernel< 64,  64, 64, 64><<<(64 *  64 + 255) / 256, 256, 0, stream>>>(w1_o1, wb1_o1);
    wconv_kernel< 64,  64, 64, 64><<<(64 *  64 + 255) / 256, 256, 0, stream>>>(w1_o2, wb1_o2);
    wconv_kernel< 64,  64, 40, 48><<<(48 *  64 + 255) / 256, 256, 0, stream>>>(w2_lin, wb2_lin);
    wconv_kernel< 40,  64, 40, 48><<<(48 *  64 + 255) / 256, 256, 0, stream>>>(w2_o1, wb2_o1);
    wconv_kernel< 40,  64, 40, 48><<<(48 *  64 + 255) / 256, 256, 0, stream>>>(w2_o2, wb2_o2);

    // ---- CSR build (reused by both layers) ----
    hipMemsetAsync(deg, 0, (size_t)n * sizeof(int), stream);
    hist_kernel<<<egrid, 256, 0, stream>>>(dst, deg, e);
    chunksum_kernel<<<nchunks, 256, 0, stream>>>(deg, chunkSum, n);
    scanchunks_kernel<<<1, 128, 0, stream>>>(chunkSum, nchunks);
    scanwithin_kernel<<<nchunks, 256, 0, stream>>>(deg, chunkSum, rowptr, n);
    fill_kernel<<<egrid, 256, 0, stream>>>(src, dst, rowptr, eidx, e);

    // ---- conv1 ----
    // h1 = x @ w1_lin.T + b            : ws0
    mv_mfma_kernel<128, 64, 128, 64, false, false><<<tgrid, 256, 0, stream>>>(
        x, wb1_lin, b1_lin, ws0, n);
    // agg1 = h1 + scatter              : ws1
    gather_kernel<HD><<<ggrid, 256, 0, stream>>>(rowptr, deg, eidx, ws0, ws1, n);
    // u1 = relu(o1 @ relu(agg1) + b)   : ws0
    mv_mfma_kernel<64, 64, 64, 64, true, true><<<tgrid, 256, 0, stream>>>(
        ws1, wb1_o1, b1_o1, ws0, n);
    // hmid = relu(o2 @ u1 + b)         : ws1
    mv_mfma_kernel<64, 64, 64, 64, false, true><<<tgrid, 256, 0, stream>>>(
        ws0, wb1_o2, b1_o2, ws1, n);

    // ---- conv2 ----
    // h2 = hmid @ w2_lin.T + b         : ws0
    mv_mfma_kernel<64, 48, 64, 40, false, false><<<tgrid, 256, 0, stream>>>(
        ws1, wb2_lin, b2_lin, ws0, n);
    // agg2 = h2 + scatter              : ws1
    gather_kernel<CD><<<ggrid, 256, 0, stream>>>(rowptr, deg, eidx, ws0, ws1, n);
    // u2 = relu(o1 @ relu(agg2) + b)   : ws0
    mv_mfma_kernel<64, 48, 40, 40, true, true><<<tgrid, 256, 0, stream>>>(
        ws1, wb2_o1, b2_o1, ws0, n);
    // out = o2 @ u2 + b                : d_out
    mv_mfma_kernel<64, 48, 40, 40, false, false><<<tgrid, 256, 0, stream>>>(
        ws0, wb2_o2, b2_o2, outp, n);
}

// Round 11
// 388.274 us; speedup vs baseline: 1.9266x; 1.2184x over previous
//
#include <hip/hip_runtime.h>

static constexpr int FIN = 128;
static constexpr int HD  = 64;
static constexpr int CD  = 40;

typedef __attribute__((ext_vector_type(8))) short short8;   // 8 bf16 = 4 VGPR
typedef __attribute__((ext_vector_type(4))) float f32x4;    // MFMA acc

__device__ __forceinline__ unsigned short f2b(float f)      // fp32->bf16 RNE
{
    union { float f; unsigned u; } x; x.f = f;
    unsigned u = x.u;
    return (unsigned short)((u + 0x7FFF + ((u >> 16) & 1)) >> 16);
}
__device__ __forceinline__ float b2f(unsigned short b)
{
    union { unsigned u; float f; } x; x.u = ((unsigned)b) << 16;
    return x.f;
}

// ---------------------------------------------------------------------------
// Weight convert: fp32 W[Oin][Kin] -> bf16 Wbf[Op][Kp], zero-padded.
// ---------------------------------------------------------------------------
template<int Kin, int Kp, int Oin, int Op>
__global__ __launch_bounds__(256)
void wconv_kernel(const float* __restrict__ W, unsigned short* __restrict__ Wbf)
{
    int i = blockIdx.x * 256 + threadIdx.x;
    if (i >= Op * Kp) return;
    int o = i / Kp, k = i - o * Kp;
    float v = (o < Oin && k < Kin) ? W[o * Kin + k] : 0.f;
    Wbf[i] = f2b(v);
}

// ---------------------------------------------------------------------------
// Dense matvec on MFMA, bf16 I/O.  Block = 256 thr = 4 waves = 64 nodes.
// Input staged to LDS as bf16 (fp32 path converts; bf16 path copies).
// Wave w: nodes [w*16,(w+1)*16) x OP outputs (OP/16 C-tiles, KP/32 MFMA each).
// Fragment layouts (m89/m91-verified):
//   A: lane = A[m=lane&15][k=quad*8+j]   (LDS, 16B reads)
//   B: lane = B[o=lane&15][k=quad*8+j]   (= Wbf row, 16B global, L1-hot)
//   D: col=lane&15 (o), row=quad*4+reg (node)
// ---------------------------------------------------------------------------
template<int KP, int OP, int K, int O, bool IN_BF16, bool IN_RELU, bool OUT_BF16, bool OUT_RELU>
__global__ __launch_bounds__(256)
void mv_mfma_kernel(const void* __restrict__ in_, const unsigned short* __restrict__ Wbf,
                    const float* __restrict__ bias, void* __restrict__ out_, int n)
{
    constexpr int KS = KP + 8;                 // bf16 elems per LDS row
    __shared__ unsigned short lds[64 * KS];
    const int t  = threadIdx.x;
    const int n0 = blockIdx.x * 64;

    if (IN_BF16) {
        const unsigned short* in = (const unsigned short*)in_;
        constexpr int V8 = KP / 8;             // 16B chunks per row
#pragma unroll
        for (int f = t; f < 64 * V8; f += 256) {
            int row = f / V8;
            int kk  = (f - row * V8) * 8;
            int gn  = n0 + row;
            union { uint4 u4; unsigned short s[8]; } v;
            if (gn < n && kk < K)
                v.u4 = *reinterpret_cast<const uint4*>(in + (size_t)gn * K + kk);
            else
                v.u4 = make_uint4(0u, 0u, 0u, 0u);
            if (IN_RELU) {
#pragma unroll
                for (int j = 0; j < 8; ++j)
                    if (v.s[j] & 0x8000) v.s[j] = 0;
            }
            *reinterpret_cast<uint4*>(&lds[row * KS + kk]) = v.u4;
        }
    } else {
        const float* in = (const float*)in_;
        constexpr int V4 = KP / 4;
#pragma unroll
        for (int f = t; f < 64 * V4; f += 256) {
            int row = f / V4;
            int k4  = (f - row * V4) * 4;
            int gn  = n0 + row;
            float4 v = make_float4(0.f, 0.f, 0.f, 0.f);
            if (gn < n && k4 < K)
                v = *reinterpret_cast<const float4*>(in + (size_t)gn * K + k4);
            if (IN_RELU) {
                v.x = fmaxf(v.x, 0.f); v.y = fmaxf(v.y, 0.f);
                v.z = fmaxf(v.z, 0.f); v.w = fmaxf(v.w, 0.f);
            }
            ushort4 b;
            b.x = f2b(v.x); b.y = f2b(v.y); b.z = f2b(v.z); b.w = f2b(v.w);
            *reinterpret_cast<ushort4*>(&lds[row * KS + k4]) = b;
        }
    }
    __syncthreads();

    const int wave = t >> 6, lane = t & 63;
    const int quad = lane >> 4, l16 = lane & 15;
    const int m0   = wave * 16;

    constexpr int NKT = KP / 32;
    short8 a[NKT];
#pragma unroll
    for (int kt = 0; kt < NKT; ++kt)
        a[kt] = *reinterpret_cast<const short8*>(
            &lds[(m0 + l16) * KS + kt * 32 + quad * 8]);

    constexpr int NOT = OP / 16;
    f32x4 acc[NOT];
#pragma unroll
    for (int ot = 0; ot < NOT; ++ot) acc[ot] = (f32x4){0.f, 0.f, 0.f, 0.f};
#pragma unroll
    for (int ot = 0; ot < NOT; ++ot) {
        const unsigned short* Wrow = Wbf + (size_t)(ot * 16 + l16) * KP + quad * 8;
#pragma unroll
        for (int kt = 0; kt < NKT; ++kt) {
            short8 b = *reinterpret_cast<const short8*>(Wrow + kt * 32);
            acc[ot] = __builtin_amdgcn_mfma_f32_16x16x32_bf16(a[kt], b, acc[ot], 0, 0, 0);
        }
    }

#pragma unroll
    for (int ot = 0; ot < NOT; ++ot) {
        int o = ot * 16 + l16;
        if (o < O) {
            float bv = bias[o];
#pragma unroll
            for (int r = 0; r < 4; ++r) {
                int node = n0 + m0 + quad * 4 + r;
                if (node < n) {
                    float v = acc[ot][r] + bv;
                    if (OUT_RELU) v = fmaxf(v, 0.f);
                    if (OUT_BF16)
                        ((unsigned short*)out_)[(size_t)node * O + o] = f2b(v);
                    else
                        ((float*)out_)[(size_t)node * O + o] = v;
                }
            }
        }
    }
}

// ---------------------------------------------------------------------------
// CSR build.
// ---------------------------------------------------------------------------
__global__ __launch_bounds__(256)
void hist_kernel(const int* __restrict__ dst, int* __restrict__ deg, int e)
{
    int i = blockIdx.x * 256 + threadIdx.x;
    if (i < e) atomicAdd(&deg[dst[i]], 1);
}

__global__ __launch_bounds__(256)
void chunksum_kernel(const int* __restrict__ deg, int* __restrict__ chunkSum, int n)
{
    __shared__ int s[256];
    int t = threadIdx.x;
    int base = blockIdx.x * 1024 + t * 4;
    int v = 0;
#pragma unroll
    for (int i = 0; i < 4; ++i) if (base + i < n) v += deg[base + i];
    s[t] = v; __syncthreads();
    for (int off = 128; off > 0; off >>= 1) {
        if (t < off) s[t] += s[t + off];
        __syncthreads();
    }
    if (t == 0) chunkSum[blockIdx.x] = s[0];
}

__global__ __launch_bounds__(128)
void scanchunks_kernel(int* __restrict__ chunkSum, int nchunks)
{
    __shared__ int s[128];
    int t = threadIdx.x;
    int v = (t < nchunks) ? chunkSum[t] : 0;
    s[t] = v; __syncthreads();
    for (int off = 1; off < 128; off <<= 1) {
        int a = (t >= off) ? s[t - off] : 0;
        __syncthreads();
        s[t] += a;
        __syncthreads();
    }
    if (t < nchunks) chunkSum[t] = s[t] - v;   // exclusive
}

__global__ __launch_bounds__(256)
void scanwithin_kernel(const int* __restrict__ deg, const int* __restrict__ chunkOff,
                       int* __restrict__ rowptr, int n)
{
    __shared__ int s[256];
    int t = threadIdx.x;
    int base = blockIdx.x * 1024 + t * 4;
    int v[4]; int sum = 0;
#pragma unroll
    for (int i = 0; i < 4; ++i) { v[i] = (base + i < n) ? deg[base + i] : 0; sum += v[i]; }
    s[t] = sum; __syncthreads();
    for (int off = 1; off < 256; off <<= 1) {
        int a = (t >= off) ? s[t - off] : 0;
        __syncthreads();
        s[t] += a;
        __syncthreads();
    }
    int p = s[t] - sum + chunkOff[blockIdx.x];
#pragma unroll
    for (int i = 0; i < 4; ++i) {
        if (base + i < n) rowptr[base + i] = p;
        p += v[i];
    }
}

__global__ __launch_bounds__(256)
void fill_kernel(const int* __restrict__ src, const int* __restrict__ dst,
                 int* __restrict__ rowptr, int* __restrict__ eidx, int e)
{
    int i = blockIdx.x * 256 + threadIdx.x;
    if (i >= e) return;
    int pos = atomicAdd(&rowptr[dst[i]], 1);
    eidx[pos] = src[i];
}

// ---------------------------------------------------------------------------
// Gather (bf16): agg[d][c] = h[d][c] + sum_{e: dst=d} h[src_e][c].
// Block = 256 = 4 waves; each wave = 4 node-groups of 16 lanes; lane covers
// 4 bf16 channels (8B load -> one 128B transaction per edge-row at D=64).
// 4 independent accumulations per wave = 4x MLP vs R10's 1-node/wave.
// fp32 accumulate in registers; bf16 store.
// ---------------------------------------------------------------------------
template<int D>
__global__ __launch_bounds__(256)
void gather_bf16_kernel(const int* __restrict__ rowptr_end, const int* __restrict__ deg,
                        const int* __restrict__ eidx, const unsigned short* __restrict__ h,
                        unsigned short* __restrict__ agg, int n)
{
    const int wave = threadIdx.x >> 6;
    const int lane = threadIdx.x & 63;
    const int grp  = lane >> 4;
    const int l16  = lane & 15;
    const int node = blockIdx.x * 16 + wave * 4 + grp;
    const int nodec = (node < n) ? node : (n - 1);
    constexpr int LPN = D / 4;               // active lanes per group
    const bool act = (l16 < LPN) && (node < n);
    const int c0 = l16 * 4;

    float a0 = 0.f, a1 = 0.f, a2 = 0.f, a3 = 0.f;
    if (act) {
        ushort4 v = *reinterpret_cast<const ushort4*>(h + (size_t)nodec * D + c0);
        a0 = b2f(v.x); a1 = b2f(v.y); a2 = b2f(v.z); a3 = b2f(v.w);
    }
    int end   = rowptr_end[nodec];
    int start = end - deg[nodec];
    if (node >= n) end = start;

    for (int base = start; base < end; base += 16) {
        int m = min(16, end - base);
        int sv = (l16 < m) ? eidx[base + l16] : 0;
        for (int j = 0; j < m; ++j) {
            int s = __shfl(sv, grp * 16 + j, 64);
            if (act) {
                ushort4 v = *reinterpret_cast<const ushort4*>(h + (size_t)s * D + c0);
                a0 += b2f(v.x); a1 += b2f(v.y); a2 += b2f(v.z); a3 += b2f(v.w);
            }
        }
    }
    if (act) {
        ushort4 o;
        o.x = f2b(a0); o.y = f2b(a1); o.z = f2b(a2); o.w = f2b(a3);
        *reinterpret_cast<ushort4*>(agg + (size_t)node * D + c0) = o;
    }
}

extern "C" void kernel_launch(void* const* d_in, const int* in_sizes, int n_in,
                              void* d_out, int out_size, void* d_ws, size_t ws_size,
                              hipStream_t stream)
{
    const float* x      = (const float*)d_in[0];
    const int*   ei     = (const int*)d_in[1];
    const float* w1_lin = (const float*)d_in[2];
    const float* b1_lin = (const float*)d_in[3];
    const float* w1_o1  = (const float*)d_in[4];
    const float* b1_o1  = (const float*)d_in[5];
    const float* w1_o2  = (const float*)d_in[6];
    const float* b1_o2  = (const float*)d_in[7];
    const float* w2_lin = (const float*)d_in[8];
    const float* b2_lin = (const float*)d_in[9];
    const float* w2_o1  = (const float*)d_in[10];
    const float* b2_o1  = (const float*)d_in[11];
    const float* w2_o2  = (const float*)d_in[12];
    const float* b2_o2  = (const float*)d_in[13];

    const int n = in_sizes[0] / FIN;   // 100000
    const int e = in_sizes[1] / 2;     // 1000000
    const int* src = ei;
    const int* dst = ei + e;

    // d_ws: two bf16 ping-pong buffers (n*64 ushorts each) + bf16 weights.
    unsigned short* ws0 = (unsigned short*)d_ws;
    unsigned short* ws1 = ws0 + (size_t)n * HD;
    unsigned short* wb  = ws1 + (size_t)n * HD;
    unsigned short* wb1_lin = wb;                 // [64][128]
    unsigned short* wb1_o1  = wb1_lin + 64 * 128; // [64][64]
    unsigned short* wb1_o2  = wb1_o1  + 64 * 64;  // [64][64]
    unsigned short* wb2_lin = wb1_o2  + 64 * 64;  // [48][64]
    unsigned short* wb2_o1  = wb2_lin + 48 * 64;  // [48][64]
    unsigned short* wb2_o2  = wb2_o1  + 48 * 64;  // [48][64]
    float* outp = (float*)d_out;

    // CSR arrays live in d_out (consumed by gather2, before final mv writes).
    int* eidx     = (int*)d_out;
    int* deg      = eidx + e;
    int* rowptr   = deg + n;
    int* chunkSum = rowptr + n;

    const int nchunks = (n + 1023) / 1024;        // 98 (<=128)
    const int egrid   = (e + 255) / 256;
    const int tgrid   = (n + 63) / 64;            // 1563 blocks
    const int ggrid   = (n + 15) / 16;            // 6250 blocks

    // ---- bf16 weight conversion (tiny) ----
    wconv_kernel<128, 128, 64, 64><<<(64 * 128 + 255) / 256, 256, 0, stream>>>(w1_lin, wb1_lin);
    wconv_kernel< 64,  64, 64, 64><<<(64 *  64 + 255) / 256, 256, 0, stream>>>(w1_o1, wb1_o1);
    wconv_kernel< 64,  64, 64, 64><<<(64 *  64 + 255) / 256, 256, 0, stream>>>(w1_o2, wb1_o2);
    wconv_kernel< 64,  64, 40, 48><<<(48 *  64 + 255) / 256, 256, 0, stream>>>(w2_lin, wb2_lin);
    wconv_kernel< 40,  64, 40, 48><<<(48 *  64 + 255) / 256, 256, 0, stream>>>(w2_o1, wb2_o1);
    wconv_kernel< 40,  64, 40, 48><<<(48 *  64 + 255) / 256, 256, 0, stream>>>(w2_o2, wb2_o2);

    // ---- CSR build (reused by both layers) ----
    hipMemsetAsync(deg, 0, (size_t)n * sizeof(int), stream);
    hist_kernel<<<egrid, 256, 0, stream>>>(dst, deg, e);
    chunksum_kernel<<<nchunks, 256, 0, stream>>>(deg, chunkSum, n);
    scanchunks_kernel<<<1, 128, 0, stream>>>(chunkSum, nchunks);
    scanwithin_kernel<<<nchunks, 256, 0, stream>>>(deg, chunkSum, rowptr, n);
    fill_kernel<<<egrid, 256, 0, stream>>>(src, dst, rowptr, eidx, e);

    // ---- conv1 ----
    // h1 = x @ w1_lin.T + b                       (fp32 in -> bf16 out) : ws0
    mv_mfma_kernel<128, 64, 128, 64, false, false, true, false><<<tgrid, 256, 0, stream>>>(
        x, wb1_lin, b1_lin, ws0, n);
    // agg1 = h1 + scatter                          (bf16)               : ws1
    gather_bf16_kernel<HD><<<ggrid, 256, 0, stream>>>(rowptr, deg, eidx, ws0, ws1, n);
    // u1 = relu(o1 @ relu(agg1) + b)               (bf16)               : ws0
    mv_mfma_kernel<64, 64, 64, 64, true, true, true, true><<<tgrid, 256, 0, stream>>>(
        ws1, wb1_o1, b1_o1, ws0, n);
    // hmid = relu(o2 @ u1 + b)  (incl. between-layer relu)              : ws1
    mv_mfma_kernel<64, 64, 64, 64, true, false, true, true><<<tgrid, 256, 0, stream>>>(
        ws0, wb1_o2, b1_o2, ws1, n);

    // ---- conv2 ----
    // h2 = hmid @ w2_lin.T + b                     (bf16)               : ws0
    mv_mfma_kernel<64, 48, 64, 40, true, false, true, false><<<tgrid, 256, 0, stream>>>(
        ws1, wb2_lin, b2_lin, ws0, n);
    // agg2 = h2 + scatter                          (bf16)               : ws1
    gather_bf16_kernel<CD><<<ggrid, 256, 0, stream>>>(rowptr, deg, eidx, ws0, ws1, n);
    // u2 = relu(o1 @ relu(agg2) + b)               (bf16)               : ws0
    mv_mfma_kernel<64, 48, 40, 40, true, true, true, true><<<tgrid, 256, 0, stream>>>(
        ws1, wb2_o1, b2_o1, ws0, n);
    // out = o2 @ u2 + b                            (bf16 in -> fp32 out): d_out
    mv_mfma_kernel<64, 48, 40, 40, true, false, false, false><<<tgrid, 256, 0, stream>>>(
        ws0, wb2_o2, b2_o2, outp, n);
}

// Round 12
// 313.017 us; speedup vs baseline: 2.3898x; 1.2404x over previous
//
#include <hip/hip_runtime.h>

static constexpr int FIN = 128;
static constexpr int HD  = 64;
static constexpr int CD  = 40;

typedef __attribute__((ext_vector_type(8))) short short8;   // 8 bf16 = 4 VGPR
typedef __attribute__((ext_vector_type(4))) float f32x4;    // MFMA acc

__device__ __forceinline__ unsigned short f2b(float f)      // fp32->bf16 RNE
{
    union { float f; unsigned u; } x; x.f = f;
    unsigned u = x.u;
    return (unsigned short)((u + 0x7FFF + ((u >> 16) & 1)) >> 16);
}
__device__ __forceinline__ float b2f(unsigned short b)
{
    union { unsigned u; float f; } x; x.u = ((unsigned)b) << 16;
    return x.f;
}

// ---------------------------------------------------------------------------
// Weight convert: fp32 W[Oin][Kin] -> bf16 Wbf[Op][Kp], zero-padded.
// ---------------------------------------------------------------------------
template<int Kin, int Kp, int Oin, int Op>
__global__ __launch_bounds__(256)
void wconv_kernel(const float* __restrict__ W, unsigned short* __restrict__ Wbf)
{
    int i = blockIdx.x * 256 + threadIdx.x;
    if (i >= Op * Kp) return;
    int o = i / Kp, k = i - o * Kp;
    float v = (o < Oin && k < Kin) ? W[o * Kin + k] : 0.f;
    Wbf[i] = f2b(v);
}

// ---------------------------------------------------------------------------
// Dense matvec on MFMA, bf16 I/O (unchanged from R11).
// ---------------------------------------------------------------------------
template<int KP, int OP, int K, int O, bool IN_BF16, bool IN_RELU, bool OUT_BF16, bool OUT_RELU>
__global__ __launch_bounds__(256)
void mv_mfma_kernel(const void* __restrict__ in_, const unsigned short* __restrict__ Wbf,
                    const float* __restrict__ bias, void* __restrict__ out_, int n)
{
    constexpr int KS = KP + 8;
    __shared__ unsigned short lds[64 * KS];
    const int t  = threadIdx.x;
    const int n0 = blockIdx.x * 64;

    if (IN_BF16) {
        const unsigned short* in = (const unsigned short*)in_;
        constexpr int V8 = KP / 8;
#pragma unroll
        for (int f = t; f < 64 * V8; f += 256) {
            int row = f / V8;
            int kk  = (f - row * V8) * 8;
            int gn  = n0 + row;
            union { uint4 u4; unsigned short s[8]; } v;
            if (gn < n && kk < K)
                v.u4 = *reinterpret_cast<const uint4*>(in + (size_t)gn * K + kk);
            else
                v.u4 = make_uint4(0u, 0u, 0u, 0u);
            if (IN_RELU) {
#pragma unroll
                for (int j = 0; j < 8; ++j)
                    if (v.s[j] & 0x8000) v.s[j] = 0;
            }
            *reinterpret_cast<uint4*>(&lds[row * KS + kk]) = v.u4;
        }
    } else {
        const float* in = (const float*)in_;
        constexpr int V4 = KP / 4;
#pragma unroll
        for (int f = t; f < 64 * V4; f += 256) {
            int row = f / V4;
            int k4  = (f - row * V4) * 4;
            int gn  = n0 + row;
            float4 v = make_float4(0.f, 0.f, 0.f, 0.f);
            if (gn < n && k4 < K)
                v = *reinterpret_cast<const float4*>(in + (size_t)gn * K + k4);
            if (IN_RELU) {
                v.x = fmaxf(v.x, 0.f); v.y = fmaxf(v.y, 0.f);
                v.z = fmaxf(v.z, 0.f); v.w = fmaxf(v.w, 0.f);
            }
            ushort4 b;
            b.x = f2b(v.x); b.y = f2b(v.y); b.z = f2b(v.z); b.w = f2b(v.w);
            *reinterpret_cast<ushort4*>(&lds[row * KS + k4]) = b;
        }
    }
    __syncthreads();

    const int wave = t >> 6, lane = t & 63;
    const int quad = lane >> 4, l16 = lane & 15;
    const int m0   = wave * 16;

    constexpr int NKT = KP / 32;
    short8 a[NKT];
#pragma unroll
    for (int kt = 0; kt < NKT; ++kt)
        a[kt] = *reinterpret_cast<const short8*>(
            &lds[(m0 + l16) * KS + kt * 32 + quad * 8]);

    constexpr int NOT = OP / 16;
    f32x4 acc[NOT];
#pragma unroll
    for (int ot = 0; ot < NOT; ++ot) acc[ot] = (f32x4){0.f, 0.f, 0.f, 0.f};
#pragma unroll
    for (int ot = 0; ot < NOT; ++ot) {
        const unsigned short* Wrow = Wbf + (size_t)(ot * 16 + l16) * KP + quad * 8;
#pragma unroll
        for (int kt = 0; kt < NKT; ++kt) {
            short8 b = *reinterpret_cast<const short8*>(Wrow + kt * 32);
            acc[ot] = __builtin_amdgcn_mfma_f32_16x16x32_bf16(a[kt], b, acc[ot], 0, 0, 0);
        }
    }

#pragma unroll
    for (int ot = 0; ot < NOT; ++ot) {
        int o = ot * 16 + l16;
        if (o < O) {
            float bv = bias[o];
#pragma unroll
            for (int r = 0; r < 4; ++r) {
                int node = n0 + m0 + quad * 4 + r;
                if (node < n) {
                    float v = acc[ot][r] + bv;
                    if (OUT_RELU) v = fmaxf(v, 0.f);
                    if (OUT_BF16)
                        ((unsigned short*)out_)[(size_t)node * O + o] = f2b(v);
                    else
                        ((float*)out_)[(size_t)node * O + o] = v;
                }
            }
        }
    }
}

// ---------------------------------------------------------------------------
// CSR build, bucketed (R12): buckets of 256 nodes (dst>>8).  Converts the
// R11 random-scatter fill (69 MB write-allocate traffic, 73 us) into
// LDS-local scatters + contiguous-region writes.
// ---------------------------------------------------------------------------
static constexpr int NBMAX = 512;   // buckets (n<=131072)
static constexpr int ACH   = 4096;  // edges per phase-A block

// A1: exact per-bucket counts (LDS-aggregated).
__global__ __launch_bounds__(256)
void bhist_kernel(const int* __restrict__ dst, int* __restrict__ bucketCount,
                  int e, int nb)
{
    __shared__ int cnt[NBMAX];
    const int t = threadIdx.x;
    for (int j = t; j < nb; j += 256) cnt[j] = 0;
    __syncthreads();
    const int i0 = blockIdx.x * ACH;
    const int i1 = min(e, i0 + ACH);
    for (int i = i0 + t; i < i1; i += 256)
        atomicAdd(&cnt[dst[i] >> 8], 1);
    __syncthreads();
    for (int j = t; j < nb; j += 256)
        if (cnt[j]) atomicAdd(&bucketCount[j], cnt[j]);
}

// exclusive scan of bucketCount -> bucketOff[0..nb]; cursor = off.
__global__ __launch_bounds__(256)
void bscan_kernel(const int* __restrict__ bucketCount, int* __restrict__ bucketOff,
                  int* __restrict__ bucketCursor, int nb)
{
    __shared__ int sA[NBMAX], sB[NBMAX];
    const int t = threadIdx.x;
#pragma unroll
    for (int s = t; s < NBMAX; s += 256) sA[s] = (s < nb) ? bucketCount[s] : 0;
    __syncthreads();
    int* pa = sA; int* pb = sB;
    for (int off = 1; off < NBMAX; off <<= 1) {
#pragma unroll
        for (int s = t; s < NBMAX; s += 256)
            pb[s] = pa[s] + ((s >= off) ? pa[s - off] : 0);
        __syncthreads();
        int* tmp = pa; pa = pb; pb = tmp;
    }
#pragma unroll
    for (int s = t; s <= nb && s < NBMAX; s += 256) {
        int v = (s == 0) ? 0 : pa[s - 1];
        bucketOff[s] = v;
        if (s < nb) bucketCursor[s] = v;
    }
    if (nb == NBMAX && t == 0) { /* unreachable for n<=131071 */ }
}

// A2: partition edges into per-bucket contiguous (dst,src) runs.
__global__ __launch_bounds__(256)
void bpart_kernel(const int* __restrict__ src, const int* __restrict__ dst,
                  int* __restrict__ bucketCursor, uint2* __restrict__ pairs,
                  int e, int nb)
{
    __shared__ int cnt[NBMAX];
    __shared__ int base[NBMAX];
    const int t = threadIdx.x;
    for (int j = t; j < nb; j += 256) cnt[j] = 0;
    __syncthreads();
    const int i0 = blockIdx.x * ACH;
    const int i1 = min(e, i0 + ACH);
    for (int i = i0 + t; i < i1; i += 256)
        atomicAdd(&cnt[dst[i] >> 8], 1);
    __syncthreads();
    for (int j = t; j < nb; j += 256) {
        int c = cnt[j];
        base[j] = c ? atomicAdd(&bucketCursor[j], c) : 0;
        cnt[j] = 0;
    }
    __syncthreads();
    for (int i = i0 + t; i < i1; i += 256) {
        int d = dst[i];
        int bkt = d >> 8;
        int pos = base[bkt] + atomicAdd(&cnt[bkt], 1);
        pairs[pos] = make_uint2((unsigned)d, (unsigned)src[i]);
    }
}

// B: per-bucket local counting sort -> rowptr_end, deg, eidx.
__global__ __launch_bounds__(256)
void bbuild_kernel(const uint2* __restrict__ pairs, const int* __restrict__ bucketOff,
                   int* __restrict__ rowptr_end, int* __restrict__ deg_g,
                   int* __restrict__ eidx, int n)
{
    __shared__ int deg[256], sA[256], sB[256], cur[256];
    const int t = threadIdx.x;
    const int b = blockIdx.x;
    const int node0 = b << 8;
    const int e0 = bucketOff[b], e1 = bucketOff[b + 1];

    deg[t] = 0;
    __syncthreads();
    for (int i = e0 + t; i < e1; i += 256)
        atomicAdd(&deg[pairs[i].x & 255], 1);
    __syncthreads();
    sA[t] = deg[t];
    __syncthreads();
    int* pa = sA; int* pb = sB;
    for (int off = 1; off < 256; off <<= 1) {
        pb[t] = pa[t] + ((t >= off) ? pa[t - off] : 0);
        __syncthreads();
        int* tmp = pa; pa = pb; pb = tmp;
    }
    // pa[t] = inclusive scan of deg
    const int node = node0 + t;
    if (node < n) {
        rowptr_end[node] = e0 + pa[t];
        deg_g[node] = deg[t];
    }
    cur[t] = pa[t] - deg[t];    // exclusive start
    __syncthreads();
    for (int i = e0 + t; i < e1; i += 256) {
        uint2 p = pairs[i];
        int pos = e0 + atomicAdd(&cur[p.x & 255], 1);
        eidx[pos] = (int)p.y;
    }
}

// ---------------------------------------------------------------------------
// Gather (bf16), unchanged from R11.
// ---------------------------------------------------------------------------
template<int D>
__global__ __launch_bounds__(256)
void gather_bf16_kernel(const int* __restrict__ rowptr_end, const int* __restrict__ deg,
                        const int* __restrict__ eidx, const unsigned short* __restrict__ h,
                        unsigned short* __restrict__ agg, int n)
{
    const int wave = threadIdx.x >> 6;
    const int lane = threadIdx.x & 63;
    const int grp  = lane >> 4;
    const int l16  = lane & 15;
    const int node = blockIdx.x * 16 + wave * 4 + grp;
    const int nodec = (node < n) ? node : (n - 1);
    constexpr int LPN = D / 4;
    const bool act = (l16 < LPN) && (node < n);
    const int c0 = l16 * 4;

    float a0 = 0.f, a1 = 0.f, a2 = 0.f, a3 = 0.f;
    if (act) {
        ushort4 v = *reinterpret_cast<const ushort4*>(h + (size_t)nodec * D + c0);
        a0 = b2f(v.x); a1 = b2f(v.y); a2 = b2f(v.z); a3 = b2f(v.w);
    }
    int end   = rowptr_end[nodec];
    int start = end - deg[nodec];
    if (node >= n) end = start;

    for (int base = start; base < end; base += 16) {
        int m = min(16, end - base);
        int sv = (l16 < m) ? eidx[base + l16] : 0;
        for (int j = 0; j < m; ++j) {
            int s = __shfl(sv, grp * 16 + j, 64);
            if (act) {
                ushort4 v = *reinterpret_cast<const ushort4*>(h + (size_t)s * D + c0);
                a0 += b2f(v.x); a1 += b2f(v.y); a2 += b2f(v.z); a3 += b2f(v.w);
            }
        }
    }
    if (act) {
        ushort4 o;
        o.x = f2b(a0); o.y = f2b(a1); o.z = f2b(a2); o.w = f2b(a3);
        *reinterpret_cast<ushort4*>(agg + (size_t)node * D + c0) = o;
    }
}

extern "C" void kernel_launch(void* const* d_in, const int* in_sizes, int n_in,
                              void* d_out, int out_size, void* d_ws, size_t ws_size,
                              hipStream_t stream)
{
    const float* x      = (const float*)d_in[0];
    const int*   ei     = (const int*)d_in[1];
    const float* w1_lin = (const float*)d_in[2];
    const float* b1_lin = (const float*)d_in[3];
    const float* w1_o1  = (const float*)d_in[4];
    const float* b1_o1  = (const float*)d_in[5];
    const float* w1_o2  = (const float*)d_in[6];
    const float* b1_o2  = (const float*)d_in[7];
    const float* w2_lin = (const float*)d_in[8];
    const float* b2_lin = (const float*)d_in[9];
    const float* w2_o1  = (const float*)d_in[10];
    const float* b2_o1  = (const float*)d_in[11];
    const float* w2_o2  = (const float*)d_in[12];
    const float* b2_o2  = (const float*)d_in[13];

    const int n = in_sizes[0] / FIN;   // 100000
    const int e = in_sizes[1] / 2;     // 1000000
    const int* src = ei;
    const int* dst = ei + e;

    // ---- d_ws layout ----
    // ws0, ws1: bf16 ping-pong node buffers (n*64 each)
    // wb*: bf16 weights (25600 ushorts)
    // pairs: E x uint2 (8 MB)   bucket arrays: ~6 KB
    unsigned short* ws0 = (unsigned short*)d_ws;
    unsigned short* ws1 = ws0 + (size_t)n * HD;
    unsigned short* wb  = ws1 + (size_t)n * HD;
    unsigned short* wb1_lin = wb;                 // [64][128]
    unsigned short* wb1_o1  = wb1_lin + 64 * 128; // [64][64]
    unsigned short* wb1_o2  = wb1_o1  + 64 * 64;  // [64][64]
    unsigned short* wb2_lin = wb1_o2  + 64 * 64;  // [48][64]
    unsigned short* wb2_o1  = wb2_lin + 48 * 64;  // [48][64]
    unsigned short* wb2_o2  = wb2_o1  + 48 * 64;  // [48][64]
    uint2* pairs        = (uint2*)(wb2_o2 + 48 * 64);
    int*   bucketCount  = (int*)(pairs + e);
    int*   bucketOff    = bucketCount + NBMAX;        // nb+1 entries
    int*   bucketCursor = bucketOff + NBMAX + 1;
    float* outp = (float*)d_out;

    // CSR arrays in d_out (consumed by gather2, before final mv writes d_out).
    int* eidx   = (int*)d_out;
    int* deg    = eidx + e;
    int* rowptr = deg + n;

    const int nb    = (n + 255) >> 8;             // 391 buckets
    const int agrid = (e + ACH - 1) / ACH;        // 245 blocks
    const int tgrid = (n + 63) / 64;              // 1563 blocks
    const int ggrid = (n + 15) / 16;              // 6250 blocks

    // ---- bf16 weight conversion (tiny) ----
    wconv_kernel<128, 128, 64, 64><<<(64 * 128 + 255) / 256, 256, 0, stream>>>(w1_lin, wb1_lin);
    wconv_kernel< 64,  64, 64, 64><<<(64 *  64 + 255) / 256, 256, 0, stream>>>(w1_o1, wb1_o1);
    wconv_kernel< 64,  64, 64, 64><<<(64 *  64 + 255) / 256, 256, 0, stream>>>(w1_o2, wb1_o2);
    wconv_kernel< 64,  64, 40, 48><<<(48 *  64 + 255) / 256, 256, 0, stream>>>(w2_lin, wb2_lin);
    wconv_kernel< 40,  64, 40, 48><<<(48 *  64 + 255) / 256, 256, 0, stream>>>(w2_o1, wb2_o1);
    wconv_kernel< 40,  64, 40, 48><<<(48 *  64 + 255) / 256, 256, 0, stream>>>(w2_o2, wb2_o2);

    // ---- CSR build (bucketed; reused by both layers) ----
    hipMemsetAsync(bucketCount, 0, NBMAX * sizeof(int), stream);
    bhist_kernel<<<agrid, 256, 0, stream>>>(dst, bucketCount, e, nb);
    bscan_kernel<<<1, 256, 0, stream>>>(bucketCount, bucketOff, bucketCursor, nb);
    bpart_kernel<<<agrid, 256, 0, stream>>>(src, dst, bucketCursor, pairs, e, nb);
    bbuild_kernel<<<nb, 256, 0, stream>>>(pairs, bucketOff, rowptr, deg, eidx, n);

    // ---- conv1 ----
    mv_mfma_kernel<128, 64, 128, 64, false, false, true, false><<<tgrid, 256, 0, stream>>>(
        x, wb1_lin, b1_lin, ws0, n);
    gather_bf16_kernel<HD><<<ggrid, 256, 0, stream>>>(rowptr, deg, eidx, ws0, ws1, n);
    mv_mfma_kernel<64, 64, 64, 64, true, true, true, true><<<tgrid, 256, 0, stream>>>(
        ws1, wb1_o1, b1_o1, ws0, n);
    mv_mfma_kernel<64, 64, 64, 64, true, false, true, true><<<tgrid, 256, 0, stream>>>(
        ws0, wb1_o2, b1_o2, ws1, n);

    // ---- conv2 ----
    mv_mfma_kernel<64, 48, 64, 40, true, false, true, false><<<tgrid, 256, 0, stream>>>(
        ws1, wb2_lin, b2_lin, ws0, n);
    gather_bf16_kernel<CD><<<ggrid, 256, 0, stream>>>(rowptr, deg, eidx, ws0, ws1, n);
    mv_mfma_kernel<64, 48, 40, 40, true, true, true, true><<<tgrid, 256, 0, stream>>>(
        ws1, wb2_o1, b2_o1, ws0, n);
    mv_mfma_kernel<64, 48, 40, 40, true, false, false, false><<<tgrid, 256, 0, stream>>>(
        ws0, wb2_o2, b2_o2, outp, n);
}